// Round 1
// baseline (1162.022 us; speedup 1.0000x reference)
//
#include <hip/hip_runtime.h>

// Problem dims (fixed by the reference)
#define NN      2048
#define IN_DIM  784
#define NFEAT   100
#define NP      2000   // MW*MP
#define NS      30
#define OUTC    2100   // NFEAT + NP

// ---------------------------------------------------------------------------
// Kernel 1: feature layer + Bernoulli rate coding.
// One thread per (n, f). Everything decision-relevant in double precision so
// that we match a float64 numpy reference exactly (all sums here are exactly
// rounded in f64 up to ~1e-16, far below any decision margin).
// ---------------------------------------------------------------------------
__global__ __launch_bounds__(256) void sbls_k1(
    const float* __restrict__ X,    // (N, IN_DIM)
    const float* __restrict__ W1,   // (IN_DIM, NFEAT)
    const float* __restrict__ B1,   // (NFEAT)
    const float* __restrict__ U,    // (NS, N, NFEAT)
    float*       __restrict__ out,  // (N, OUTC)
    unsigned*    __restrict__ colmask) // (N*NFEAT) 30-bit spike masks
{
    int tid = blockIdx.x * blockDim.x + threadIdx.x;
    if (tid >= NN * NFEAT) return;
    int n = tid / NFEAT;
    int f = tid - n * NFEAT;

    const float* xr = X + (size_t)n * IN_DIM;
    double acc = (double)B1[f];
    for (int k = 0; k < IN_DIM; ++k)
        acc += (double)xr[k] * (double)W1[k * NFEAT + f];

    // sigmoid(acc/3) in double
    double z = 1.0 / (1.0 + exp(-acc / 3.0));

    unsigned m = 0;
    int cnt = 0;
    for (int s = 0; s < NS; ++s) {
        float u = U[(size_t)s * (NN * NFEAT) + tid];
        int sp = ((double)u < z) ? 1 : 0;
        m |= (unsigned)sp << s;
        cnt += sp;
    }
    colmask[tid] = m;
    out[(size_t)n * OUTC + f] = (float)((double)cnt / 30.0);
}

// ---------------------------------------------------------------------------
// Kernel 2: enhancement GEMM (binary A) fused with LIF scan + rate mean.
// Block = one n and a 256-wide tile of p. Each thread keeps 30 f64
// accumulators (one per timestep). The spike mask bits are wave-uniform:
// readfirstlane forces SALU tests so zero bits cost only a scalar branch.
// ---------------------------------------------------------------------------
__global__ __launch_bounds__(256) void sbls_k2(
    const float*    __restrict__ W2,   // (NFEAT, NP)
    const float*    __restrict__ B2,   // (NP)
    const unsigned* __restrict__ colmask, // (N*NFEAT)
    float*          __restrict__ out)  // (N, OUTC)
{
    __shared__ unsigned smask[NFEAT];
    const int n    = blockIdx.x;      // 0..NN-1
    const int tile = blockIdx.y;      // 0..7
    const int p    = tile * 256 + threadIdx.x;

    if (threadIdx.x < NFEAT)
        smask[threadIdx.x] = colmask[n * NFEAT + threadIdx.x];
    __syncthreads();
    if (p >= NP) return;

    double h[NS];
    const double b = (double)B2[p];
#pragma unroll
    for (int s = 0; s < NS; ++s) h[s] = b;

    for (int f = 0; f < NFEAT; ++f) {
        unsigned m = __builtin_amdgcn_readfirstlane(smask[f]); // wave-uniform
        double w = (double)W2[f * NP + p];
#pragma unroll
        for (int s = 0; s < NS; ++s)
            if (m & (1u << s)) h[s] += w;
    }

    // LIF: mem = beta*mem + x - spk*thresh ; spk = mem > thresh
    double mem = 0.0, spk = 0.0;
    int cnt = 0;
#pragma unroll
    for (int s = 0; s < NS; ++s) {
        mem = 0.9 * mem + h[s] - spk;
        bool sp = mem > 1.0;
        spk = sp ? 1.0 : 0.0;
        cnt += sp;
    }
    out[(size_t)n * OUTC + NFEAT + p] = (float)((double)cnt / 30.0);
}

// ---------------------------------------------------------------------------
extern "C" void kernel_launch(void* const* d_in, const int* in_sizes, int n_in,
                              void* d_out, int out_size, void* d_ws, size_t ws_size,
                              hipStream_t stream) {
    const float* X  = (const float*)d_in[0];
    const float* W1 = (const float*)d_in[1];
    const float* B1 = (const float*)d_in[2];
    const float* W2 = (const float*)d_in[3];
    const float* B2 = (const float*)d_in[4];
    const float* U  = (const float*)d_in[5];
    float* out = (float*)d_out;

    unsigned* colmask = (unsigned*)d_ws;  // NN*NFEAT u32 = 819.2 KB

    {
        int total = NN * NFEAT;
        int blocks = (total + 255) / 256;
        sbls_k1<<<blocks, 256, 0, stream>>>(X, W1, B1, U, out, colmask);
    }
    {
        dim3 grid(NN, (NP + 255) / 256);
        sbls_k2<<<grid, 256, 0, stream>>>(W2, B2, colmask, out);
    }
}

// Round 2
// 742.802 us; speedup vs baseline: 1.5644x; 1.5644x over previous
//
#include <hip/hip_runtime.h>

// Problem dims (fixed by the reference)
#define NN      2048
#define IN_DIM  784
#define NFEAT   100
#define NP      2000   // MW*MP
#define NS      30
#define OUTC    2100   // NFEAT + NP

// ---------------------------------------------------------------------------
// Kernel 1: feature layer + Bernoulli rate coding.
// One thread per (n, f). All decision-relevant math in f64 (margins are
// ~1e-1..1e-3; f64 rounding ~1e-16 -> zero expected decision flips vs the
// float64 numpy reference).
// ---------------------------------------------------------------------------
__global__ __launch_bounds__(256) void sbls_k1(
    const float* __restrict__ X,    // (N, IN_DIM)
    const float* __restrict__ W1,   // (IN_DIM, NFEAT)
    const float* __restrict__ B1,   // (NFEAT)
    const float* __restrict__ U,    // (NS, N, NFEAT)
    float*       __restrict__ out,  // (N, OUTC)
    unsigned*    __restrict__ colmask) // (N*NFEAT) 30-bit spike masks
{
    int tid = blockIdx.x * blockDim.x + threadIdx.x;
    if (tid >= NN * NFEAT) return;
    int n = tid / NFEAT;
    int f = tid - n * NFEAT;

    const float* xr = X + (size_t)n * IN_DIM;
    double acc = (double)B1[f];
    for (int k = 0; k < IN_DIM; ++k)
        acc += (double)xr[k] * (double)W1[k * NFEAT + f];

    double z = 1.0 / (1.0 + exp(-acc / 3.0));

    unsigned m = 0;
    int cnt = 0;
    for (int s = 0; s < NS; ++s) {
        float u = U[(size_t)s * (NN * NFEAT) + tid];
        int sp = ((double)u < z) ? 1 : 0;
        m |= (unsigned)sp << s;
        cnt += sp;
    }
    colmask[tid] = m;
    out[(size_t)n * OUTC + f] = (float)((double)cnt / 30.0);
}

// ---------------------------------------------------------------------------
// Kernel 2: binary GEMM fused with LIF scan + rate mean.
// Selection-as-data: per block (one n), build an LDS table k[f][s] in {0,1}
// as f64. Inner loop is then a pure v_fmac_f64 stream:
//     h[s] += k[f][s] * w64[f]
// The DS pipe (uniform broadcast reads of k) runs in parallel with the f64
// VALU pipe, so the fma is the only VALU cost per (f,s) quad.
// +0.0*w contributes exactly 0 to the sum (no -0.0 sources), so the result
// is bit-identical to the skip-zeros version that passed with absmax 0.
// ---------------------------------------------------------------------------
__global__ __launch_bounds__(256, 2) void sbls_k2(
    const float*    __restrict__ W2,   // (NFEAT, NP)
    const float*    __restrict__ B2,   // (NP)
    const unsigned* __restrict__ colmask, // (N*NFEAT)
    float*          __restrict__ out)  // (N, OUTC)
{
    __shared__ double klds[NFEAT * NS];   // 24 KB, [f][s] row-major
    const int n    = blockIdx.x;      // 0..NN-1
    const int tile = blockIdx.y;      // 0..7
    const int p    = tile * 256 + threadIdx.x;

    // Build selector table: 3000 entries / 256 threads.
    for (int i = threadIdx.x; i < NFEAT * NS; i += 256) {
        int f = i / NS;
        int s = i - f * NS;
        unsigned m = colmask[n * NFEAT + f];
        klds[i] = (double)((m >> s) & 1u);
    }
    __syncthreads();
    if (p >= NP) return;

    double h[NS];
    const double b = (double)B2[p];
#pragma unroll
    for (int s = 0; s < NS; ++s) h[s] = b;

    for (int f = 0; f < NFEAT; ++f) {
        const double w = (double)W2[f * NP + p];
        const double* kf = klds + f * NS;
#pragma unroll
        for (int s = 0; s < NS; ++s)
            h[s] = fma(kf[s], w, h[s]);
    }

    // LIF: mem = beta*mem + x - spk*thresh ; spk = mem > thresh
    double mem = 0.0, spk = 0.0;
    int cnt = 0;
#pragma unroll
    for (int s = 0; s < NS; ++s) {
        mem = 0.9 * mem + h[s] - spk;
        bool sp = mem > 1.0;
        spk = sp ? 1.0 : 0.0;
        cnt += sp;
    }
    out[(size_t)n * OUTC + NFEAT + p] = (float)((double)cnt / 30.0);
}

// ---------------------------------------------------------------------------
extern "C" void kernel_launch(void* const* d_in, const int* in_sizes, int n_in,
                              void* d_out, int out_size, void* d_ws, size_t ws_size,
                              hipStream_t stream) {
    const float* X  = (const float*)d_in[0];
    const float* W1 = (const float*)d_in[1];
    const float* B1 = (const float*)d_in[2];
    const float* W2 = (const float*)d_in[3];
    const float* B2 = (const float*)d_in[4];
    const float* U  = (const float*)d_in[5];
    float* out = (float*)d_out;

    unsigned* colmask = (unsigned*)d_ws;  // NN*NFEAT u32 = 819.2 KB

    {
        int total = NN * NFEAT;
        int blocks = (total + 255) / 256;
        sbls_k1<<<blocks, 256, 0, stream>>>(X, W1, B1, U, out, colmask);
    }
    {
        dim3 grid(NN, (NP + 255) / 256);
        sbls_k2<<<grid, 256, 0, stream>>>(W2, B2, colmask, out);
    }
}

// Round 3
// 741.432 us; speedup vs baseline: 1.5673x; 1.0018x over previous
//
#include <hip/hip_runtime.h>

// Problem dims (fixed by the reference)
#define NN      2048
#define IN_DIM  784
#define NFEAT   100
#define NP      2000   // MW*MP
#define NS      30
#define OUTC    2100   // NFEAT + NP

typedef double double2v __attribute__((ext_vector_type(2)));

// ---------------------------------------------------------------------------
// Kernel 1: feature layer + Bernoulli rate coding (f64 decisions).
// ---------------------------------------------------------------------------
__global__ __launch_bounds__(256) void sbls_k1(
    const float* __restrict__ X,    // (N, IN_DIM)
    const float* __restrict__ W1,   // (IN_DIM, NFEAT)
    const float* __restrict__ B1,   // (NFEAT)
    const float* __restrict__ U,    // (NS, N, NFEAT)
    float*       __restrict__ out,  // (N, OUTC)
    unsigned*    __restrict__ colmask) // (N*NFEAT) 30-bit spike masks
{
    int tid = blockIdx.x * blockDim.x + threadIdx.x;
    if (tid >= NN * NFEAT) return;
    int n = tid / NFEAT;
    int f = tid - n * NFEAT;

    const float* xr = X + (size_t)n * IN_DIM;
    double acc = (double)B1[f];
    for (int k = 0; k < IN_DIM; ++k)
        acc += (double)xr[k] * (double)W1[k * NFEAT + f];

    double z = 1.0 / (1.0 + exp(-acc / 3.0));

    unsigned m = 0;
    int cnt = 0;
    for (int s = 0; s < NS; ++s) {
        float u = U[(size_t)s * (NN * NFEAT) + tid];
        int sp = ((double)u < z) ? 1 : 0;
        m |= (unsigned)sp << s;
        cnt += sp;
    }
    colmask[tid] = m;
    out[(size_t)n * OUTC + f] = (float)((double)cnt / 30.0);
}

// ---------------------------------------------------------------------------
// Kernel 2: binary GEMM fused with LIF scan + rate mean.
// Selector table k[f][s] in {0.0,1.0} f64 in LDS; inner loop is pure
// v_fma_f64 with the selector streamed over the DS pipe. This round: read
// k as double2 (ds_read_b128) to halve DS instruction count — round 2
// showed the DS pipe, not the VALU, was the limiter (VALUBusy 58%).
// Bit-identical math to the passing round-2 kernel.
// ---------------------------------------------------------------------------
__global__ __launch_bounds__(256, 2) void sbls_k2(
    const float*    __restrict__ W2,   // (NFEAT, NP)
    const float*    __restrict__ B2,   // (NP)
    const unsigned* __restrict__ colmask, // (N*NFEAT)
    float*          __restrict__ out)  // (N, OUTC)
{
    __shared__ __align__(16) double klds[NFEAT * NS];   // 24 KB, [f][s]
    const int n    = blockIdx.x;      // 0..NN-1
    const int tile = blockIdx.y;      // 0..7
    const int p    = tile * 256 + threadIdx.x;

    // Build selector table: 3000 entries / 256 threads.
    for (int i = threadIdx.x; i < NFEAT * NS; i += 256) {
        int f = i / NS;
        int s = i - f * NS;
        unsigned m = colmask[n * NFEAT + f];
        klds[i] = (double)((m >> s) & 1u);
    }
    __syncthreads();
    if (p >= NP) return;

    double h[NS];
    const double b = (double)B2[p];
#pragma unroll
    for (int s = 0; s < NS; ++s) h[s] = b;

    for (int f = 0; f < NFEAT; ++f) {
        const double w = (double)W2[f * NP + p];
        // f*NS*8 = f*240 bytes, 240 % 16 == 0 -> every row is 16B aligned.
        const double2v* kf2 = (const double2v*)(klds + f * NS);
#pragma unroll
        for (int j = 0; j < NS / 2; ++j) {
            double2v k2 = kf2[j];                 // ds_read_b128
            h[2 * j]     = fma(k2.x, w, h[2 * j]);
            h[2 * j + 1] = fma(k2.y, w, h[2 * j + 1]);
        }
    }

    // LIF: mem = beta*mem + x - spk*thresh ; spk = mem > thresh
    double mem = 0.0, spk = 0.0;
    int cnt = 0;
#pragma unroll
    for (int s = 0; s < NS; ++s) {
        mem = 0.9 * mem + h[s] - spk;
        bool sp = mem > 1.0;
        spk = sp ? 1.0 : 0.0;
        cnt += sp;
    }
    out[(size_t)n * OUTC + NFEAT + p] = (float)((double)cnt / 30.0);
}

// ---------------------------------------------------------------------------
extern "C" void kernel_launch(void* const* d_in, const int* in_sizes, int n_in,
                              void* d_out, int out_size, void* d_ws, size_t ws_size,
                              hipStream_t stream) {
    const float* X  = (const float*)d_in[0];
    const float* W1 = (const float*)d_in[1];
    const float* B1 = (const float*)d_in[2];
    const float* W2 = (const float*)d_in[3];
    const float* B2 = (const float*)d_in[4];
    const float* U  = (const float*)d_in[5];
    float* out = (float*)d_out;

    unsigned* colmask = (unsigned*)d_ws;  // NN*NFEAT u32 = 819.2 KB

    {
        int total = NN * NFEAT;
        int blocks = (total + 255) / 256;
        sbls_k1<<<blocks, 256, 0, stream>>>(X, W1, B1, U, out, colmask);
    }
    {
        dim3 grid(NN, (NP + 255) / 256);
        sbls_k2<<<grid, 256, 0, stream>>>(W2, B2, colmask, out);
    }
}

// Round 5
// 509.418 us; speedup vs baseline: 2.2811x; 1.4555x over previous
//
#include <hip/hip_runtime.h>

// Problem dims (fixed by the reference)
#define NN      2048
#define IN_DIM  784
#define NFEAT   100
#define NP      2000   // MW*MP
#define NS      30
#define OUTC    2100   // NFEAT + NP

typedef double f64x4 __attribute__((ext_vector_type(4)));

__device__ __forceinline__ f64x4 mfma_f64(double a, double b, f64x4 c) {
#if __has_builtin(__builtin_amdgcn_mfma_f64_16x16x4f64)
    return __builtin_amdgcn_mfma_f64_16x16x4f64(a, b, c, 0, 0, 0);
#else
    asm volatile("v_mfma_f64_16x16x4_f64 %0, %1, %2, %0"
                 : "+v"(c) : "v"(a), "v"(b));
    return c;
#endif
}

// ---------------------------------------------------------------------------
// Kernel 1: feature layer + Bernoulli rate coding (f64 decisions). Unchanged.
// ---------------------------------------------------------------------------
__global__ __launch_bounds__(256) void sbls_k1(
    const float* __restrict__ X,    // (N, IN_DIM)
    const float* __restrict__ W1,   // (IN_DIM, NFEAT)
    const float* __restrict__ B1,   // (NFEAT)
    const float* __restrict__ U,    // (NS, N, NFEAT)
    float*       __restrict__ out,  // (N, OUTC)
    unsigned*    __restrict__ colmask) // (N*NFEAT) 30-bit spike masks
{
    int tid = blockIdx.x * blockDim.x + threadIdx.x;
    if (tid >= NN * NFEAT) return;
    int n = tid / NFEAT;
    int f = tid - n * NFEAT;

    const float* xr = X + (size_t)n * IN_DIM;
    double acc = (double)B1[f];
    for (int k = 0; k < IN_DIM; ++k)
        acc += (double)xr[k] * (double)W1[k * NFEAT + f];

    double z = 1.0 / (1.0 + exp(-acc / 3.0));

    unsigned m = 0;
    int cnt = 0;
    for (int s = 0; s < NS; ++s) {
        float u = U[(size_t)s * (NN * NFEAT) + tid];
        int sp = ((double)u < z) ? 1 : 0;
        m |= (unsigned)sp << s;
        cnt += sp;
    }
    colmask[tid] = m;
    out[(size_t)n * OUTC + f] = (float)((double)cnt / 30.0);
}

// ---------------------------------------------------------------------------
// Kernel 2: binary GEMM via f64 MFMA with RUNTIME-PROBED D layout.
//   h[s][p] = sum_f K[s][f] * W2[f][p]   (B2 added in the LIF reader)
// Round-4 failed with a "time-permutation" error signature -> the f64
// 16x16x4 C/D (or A) row mapping differs from the bf16-verified one.
// Fix: two probe MFMAs decode, per (lane, reg), the actual (s-row, p-col)
// each accumulator slot holds:
//   probe1: A = lane&15, B = 1  -> D = 4*srow
//   probe2: A = 1, B = lane&15  -> D = 4*pcol
// The epilogue scatters acc via (srow, pcol) -> correct under ANY within-
// instruction row/col permutation. Only assumption: A and B use the same
// lane->k grouping (a mismatch would scramble feature pairing, contradicted
// by round-4's near-miss).
// ---------------------------------------------------------------------------
__global__ __launch_bounds__(256, 2) void sbls_k2(
    const float*    __restrict__ W2,   // (NFEAT, NP)
    const float*    __restrict__ B2,   // (NP)
    const unsigned* __restrict__ colmask, // (N*NFEAT)
    float*          __restrict__ out)  // (N, OUTC)
{
    __shared__ unsigned smask[NFEAT];
    __shared__ double h_lds[32][130];   // +2 pad

    const int n     = blockIdx.x;
    const int chunk = blockIdx.y;       // 0..7 (chunk 7 partial)
    const int l  = threadIdx.x & 63;
    const int wv = threadIdx.x >> 6;    // wave 0..3
    const int lm = l & 15;
    const int lg = l >> 4;

    if (threadIdx.x < NFEAT)
        smask[threadIdx.x] = colmask[n * NFEAT + threadIdx.x];

    // --- layout probes (self-calibrating, ~free) ---
    f64x4 zero = (f64x4){0.0, 0.0, 0.0, 0.0};
    f64x4 d1 = mfma_f64((double)lm, 1.0, zero);   // D = 4*srow
    f64x4 d2 = mfma_f64(1.0, (double)lm, zero);   // D = 4*pcol
    int srow[4], pcol[4];
#pragma unroll
    for (int r = 0; r < 4; ++r) {
        int a = (int)(d1[r] * 0.25);
        int b = (int)(d2[r] * 0.25);
        srow[r] = (a < 0) ? 0 : (a > 15 ? 15 : a);
        pcol[r] = (b < 0) ? 0 : (b > 15 ? 15 : b);
    }

    __syncthreads();

    // Per-wave: 4 p-tiles x 2 s-tiles -> 8 accumulators
    f64x4 acc[2][4];
    int pclamp[4];
#pragma unroll
    for (int i = 0; i < 4; ++i) {
        int p = chunk * 256 + (wv * 4 + i) * 16 + lm;
        pclamp[i] = (p < NP) ? p : (NP - 1);
        acc[0][i] = zero;
        acc[1][i] = zero;
    }

    for (int kt = 0; kt < 25; ++kt) {
        unsigned mw = smask[kt * 4 + lg];
        double a0 = ((mw >> lm) & 1u) ? 1.0 : 0.0;         // s = lm
        double a1 = ((mw >> (lm + 16)) & 1u) ? 1.0 : 0.0;  // s = lm+16
        const float* wrow = W2 + (size_t)(kt * 4 + lg) * NP;
#pragma unroll
        for (int i = 0; i < 4; ++i) {
            double b = (double)wrow[pclamp[i]];
            acc[0][i] = mfma_f64(a0, b, acc[0][i]);
            acc[1][i] = mfma_f64(a1, b, acc[1][i]);
        }
    }

    // Epilogue: two half-passes of 128 columns (waves 0,1 then 2,3).
#pragma unroll
    for (int hp = 0; hp < 2; ++hp) {
        __syncthreads();
        if ((wv >> 1) == hp) {
#pragma unroll
            for (int i = 0; i < 4; ++i) {
                int tloc = (wv & 1) * 4 + i;      // 0..7 within half
#pragma unroll
                for (int st = 0; st < 2; ++st)
#pragma unroll
                    for (int r = 0; r < 4; ++r)
                        h_lds[st * 16 + srow[r]][tloc * 16 + pcol[r]] = acc[st][i][r];
            }
        }
        __syncthreads();
        if (threadIdx.x < 128) {
            int p = chunk * 256 + hp * 128 + threadIdx.x;
            if (p < NP) {
                double b2d = (double)B2[p];
                double mem = 0.0, spk = 0.0;
                int cnt = 0;
#pragma unroll
                for (int s = 0; s < NS; ++s) {
                    double h = h_lds[s][threadIdx.x] + b2d;
                    mem = 0.9 * mem + h - spk;
                    bool sp = mem > 1.0;
                    spk = sp ? 1.0 : 0.0;
                    cnt += sp;
                }
                out[(size_t)n * OUTC + NFEAT + p] = (float)((double)cnt / 30.0);
            }
        }
    }
}

// ---------------------------------------------------------------------------
extern "C" void kernel_launch(void* const* d_in, const int* in_sizes, int n_in,
                              void* d_out, int out_size, void* d_ws, size_t ws_size,
                              hipStream_t stream) {
    const float* X  = (const float*)d_in[0];
    const float* W1 = (const float*)d_in[1];
    const float* B1 = (const float*)d_in[2];
    const float* W2 = (const float*)d_in[3];
    const float* B2 = (const float*)d_in[4];
    const float* U  = (const float*)d_in[5];
    float* out = (float*)d_out;

    unsigned* colmask = (unsigned*)d_ws;  // NN*NFEAT u32 = 819.2 KB

    {
        int total = NN * NFEAT;
        int blocks = (total + 255) / 256;
        sbls_k1<<<blocks, 256, 0, stream>>>(X, W1, B1, U, out, colmask);
    }
    {
        dim3 grid(NN, (NP + 255) / 256);
        sbls_k2<<<grid, 256, 0, stream>>>(W2, B2, colmask, out);
    }
}